// Round 1
// baseline (1598.200 us; speedup 1.0000x reference)
//
#include <hip/hip_runtime.h>

#define N_NODES 100000
#define N_EDGES 3200000
#define N_GRAPHS 256
#define HID 64

// ---------------- CSR build ----------------

__global__ void k_zero_int(int* p, int n) {
    int i = blockIdx.x * blockDim.x + threadIdx.x;
    if (i < n) p[i] = 0;
}

__global__ void k_count(const int* __restrict__ dst, int* __restrict__ cnt, int n) {
    int i = blockIdx.x * blockDim.x + threadIdx.x;
    if (i < n) atomicAdd(&cnt[dst[i]], 1);
}

__global__ void k_dinv(const int* __restrict__ cnt, float* __restrict__ dinv, int n) {
    int i = blockIdx.x * blockDim.x + threadIdx.x;
    if (i < n) dinv[i] = rsqrtf((float)cnt[i] + 1.0f);  // deg = indeg + self-loop
}

// single-block exclusive scan (1024 threads, Hillis-Steele per chunk)
__global__ void k_scan(const int* __restrict__ cnt, int* __restrict__ row_ptr,
                       int* __restrict__ cursor, int n) {
    __shared__ int s[1024];
    __shared__ int carry;
    int t = threadIdx.x;
    if (t == 0) carry = 0;
    __syncthreads();
    for (int base = 0; base < n; base += 1024) {
        int idx = base + t;
        int v = (idx < n) ? cnt[idx] : 0;
        s[t] = v;
        __syncthreads();
        for (int off = 1; off < 1024; off <<= 1) {
            int add = (t >= off) ? s[t - off] : 0;
            __syncthreads();
            s[t] += add;
            __syncthreads();
        }
        int inc = s[t];
        int total = s[1023];
        int ex = inc - v;
        int c = carry;
        if (idx < n) { row_ptr[idx] = c + ex; cursor[idx] = c + ex; }
        __syncthreads();
        if (t == 0) carry = c + total;
        __syncthreads();
    }
    if (t == 0) row_ptr[n] = carry;
}

__global__ void k_fill(const int* __restrict__ src, const int* __restrict__ dst,
                       int* __restrict__ cursor, int* __restrict__ esrc, int n) {
    int i = blockIdx.x * blockDim.x + threadIdx.x;
    if (i < n) {
        int d = dst[i];
        int pos = atomicAdd(&cursor[d], 1);
        esrc[pos] = src[i];
    }
}

// ---------------- GCN layers ----------------

// layer-1 transform: B[i,:] = (x[i,0:8] @ W1[8,64]) * dinv[i]
__global__ __launch_bounds__(256) void k_transform1(
        const float* __restrict__ x, const float* __restrict__ W,
        const float* __restrict__ dinv, float* __restrict__ B) {
    int wid = (blockIdx.x * 256 + threadIdx.x) >> 6;
    int lane = threadIdx.x & 63;
    if (wid >= N_NODES) return;
    const float* xr = x + wid * 8;
    float acc = 0.f;
#pragma unroll
    for (int k = 0; k < 8; ++k) acc += xr[k] * W[k * 64 + lane];
    B[wid * 64 + lane] = acc * dinv[wid];
}

// 64x64 transform: B[i,:] = (A[i,:] @ W) * dinv[i], W staged in LDS
__global__ __launch_bounds__(256) void k_transform64(
        const float* __restrict__ A, const float* __restrict__ W,
        const float* __restrict__ dinv, float* __restrict__ B) {
    __shared__ float Wl[64 * 64];
    for (int j = threadIdx.x; j < 64 * 64; j += 256) Wl[j] = W[j];
    __syncthreads();
    int wid = (blockIdx.x * 256 + threadIdx.x) >> 6;
    int lane = threadIdx.x & 63;
    if (wid >= N_NODES) return;
    const float* ar = A + wid * 64;
    float acc = 0.f;
#pragma unroll
    for (int k = 0; k < 64; ++k) acc += ar[k] * Wl[k * 64 + lane];
    B[wid * 64 + lane] = acc * dinv[wid];
}

// aggregate: A[i,:] = act( dinv[i] * (B[i,:] + sum_{e:dst=i} B[esrc[e],:]) + bias )
template <int RELU>
__global__ __launch_bounds__(256) void k_aggregate(
        const float* __restrict__ B, float* __restrict__ A,
        const float* __restrict__ dinv, const int* __restrict__ rp,
        const int* __restrict__ esrc, const float* __restrict__ bias) {
    int wid = (blockIdx.x * 256 + threadIdx.x) >> 6;
    int lane = threadIdx.x & 63;
    if (wid >= N_NODES) return;
    int beg = rp[wid], end = rp[wid + 1];
    float acc = B[wid * 64 + lane];  // self loop
    for (int e0 = beg; e0 < end; e0 += 64) {
        int myE = e0 + lane;
        int s = (myE < end) ? esrc[myE] : 0;
        int c = min(64, end - e0);
        for (int j = 0; j < c; ++j) {
            int sj = __shfl(s, j);
            acc += B[sj * 64 + lane];
        }
    }
    float out = dinv[wid] * acc + bias[lane];
    A[wid * 64 + lane] = RELU ? fmaxf(out, 0.f) : out;
}

// ---------------- pooling + heads ----------------

__global__ void k_gstart(const int* __restrict__ batch, int* __restrict__ gstart) {
    int g = threadIdx.x;  // one block, 256 threads
    int lo = 0, hi = N_NODES;
    while (lo < hi) {
        int mid = (lo + hi) >> 1;
        if (batch[mid] < g) lo = mid + 1; else hi = mid;
    }
    gstart[g] = lo;
    if (g == 0) gstart[N_GRAPHS] = N_NODES;
}

__global__ __launch_bounds__(256) void k_pool(
        const float* __restrict__ A, const int* __restrict__ gstart,
        float* __restrict__ xgp) {
    int g = blockIdx.x;
    int beg = gstart[g], end = gstart[g + 1];
    int lane = threadIdx.x & 63, grp = threadIdx.x >> 6;
    float acc = 0.f;
    for (int r = beg + grp; r < end; r += 4) acc += A[r * 64 + lane];
    __shared__ float l[256];
    l[threadIdx.x] = acc;
    __syncthreads();
    if (threadIdx.x < 64) {
        float s = l[threadIdx.x] + l[threadIdx.x + 64] + l[threadIdx.x + 128] + l[threadIdx.x + 192];
        float c = (float)(end - beg);
        xgp[g * 64 + threadIdx.x] = s / fmaxf(c, 1.f);
    }
}

// x_global = relu(xgp @ Wg + bg), one wave per graph
__global__ __launch_bounds__(256) void k_xglobal(
        const float* __restrict__ xgp, const float* __restrict__ Wg,
        const float* __restrict__ bg, float* __restrict__ xg) {
    int wid = (blockIdx.x * 256 + threadIdx.x) >> 6;
    int lane = threadIdx.x & 63;
    if (wid >= N_GRAPHS) return;
    float acc = bg[lane];
#pragma unroll 16
    for (int k = 0; k < 64; ++k) acc += xgp[wid * 64 + k] * Wg[k * 64 + lane];
    xg[wid * 64 + lane] = fmaxf(acc, 0.f);
}

// heuristic = relu(xg @ Wh1 + bh1) @ Wh2 + bh2, one thread per graph
__global__ void k_heuristic(const float* __restrict__ xg,
                            const float* __restrict__ Wh1, const float* __restrict__ bh1,
                            const float* __restrict__ Wh2, const float* __restrict__ bh2,
                            float* __restrict__ out) {
    int g = threadIdx.x;  // one block, 256 threads
    const float* r = xg + g * 64;
    float acc = bh2[0];
    for (int j = 0; j < 32; ++j) {
        float hj = bh1[j];
#pragma unroll 16
        for (int k = 0; k < 64; ++k) hj += r[k] * Wh1[k * 32 + j];
        acc += fmaxf(hj, 0.f) * Wh2[j];
    }
    out[g] = acc;
}

// move_logits + block_priority heads, one wave per node
__global__ __launch_bounds__(256) void k_heads(
        const float* __restrict__ h,
        const float* __restrict__ Wm1, const float* __restrict__ bm1,
        const float* __restrict__ Wm2, const float* __restrict__ bm2,
        const float* __restrict__ Wp1, const float* __restrict__ bp1,
        const float* __restrict__ Wp2, const float* __restrict__ bp2,
        float* __restrict__ out_m, float* __restrict__ out_p) {
    int wid = (blockIdx.x * 256 + threadIdx.x) >> 6;
    int lane = threadIdx.x & 63;
    if (wid >= N_NODES) return;
    const float* hr = h + wid * 64;

    // hidden m1[f] = relu(h . Wm1[:,f] + bm1[f])
    float m = bm1[lane];
#pragma unroll 16
    for (int k = 0; k < 64; ++k) m += hr[k] * Wm1[k * 64 + lane];
    m = fmaxf(m, 0.f);

#pragma unroll
    for (int j = 0; j < 9; ++j) {
        float p = m * Wm2[lane * 9 + j];
#pragma unroll
        for (int off = 32; off; off >>= 1) p += __shfl_xor(p, off);
        if (lane == j) out_m[wid * 9 + j] = p + bm2[j];
    }

    float pv = 0.f;
    if (lane < 32) {
        float p1 = bp1[lane];
#pragma unroll 16
        for (int k = 0; k < 64; ++k) p1 += hr[k] * Wp1[k * 32 + lane];
        pv = fmaxf(p1, 0.f) * Wp2[lane];
    }
#pragma unroll
    for (int off = 32; off; off >>= 1) pv += __shfl_xor(pv, off);
    if (lane == 0) out_p[wid] = pv + bp2[0];
}

// ---------------- launch ----------------

extern "C" void kernel_launch(void* const* d_in, const int* in_sizes, int n_in,
                              void* d_out, int out_size, void* d_ws, size_t ws_size,
                              hipStream_t stream) {
    const float* x    = (const float*)d_in[0];
    const int*   ei   = (const int*)d_in[1];
    const int*   batch= (const int*)d_in[2];
    const float* W1   = (const float*)d_in[3];
    const float* b1   = (const float*)d_in[4];
    const float* W2   = (const float*)d_in[5];
    const float* b2   = (const float*)d_in[6];
    const float* W3   = (const float*)d_in[7];
    const float* b3   = (const float*)d_in[8];
    const float* Wg   = (const float*)d_in[9];
    const float* bg   = (const float*)d_in[10];
    const float* Wh1  = (const float*)d_in[11];
    const float* bh1  = (const float*)d_in[12];
    const float* Wh2  = (const float*)d_in[13];
    const float* bh2  = (const float*)d_in[14];
    const float* Wm1  = (const float*)d_in[15];
    const float* bm1  = (const float*)d_in[16];
    const float* Wm2  = (const float*)d_in[17];
    const float* bm2  = (const float*)d_in[18];
    const float* Wp1  = (const float*)d_in[19];
    const float* bp1  = (const float*)d_in[20];
    const float* Wp2  = (const float*)d_in[21];
    const float* bp2  = (const float*)d_in[22];

    const int* e_src = ei;
    const int* e_dst = ei + N_EDGES;

    // workspace carve-up (all 256B-aligned)
    char* ws = (char*)d_ws;
    size_t off = 0;
    auto alloc = [&](size_t bytes) {
        void* p = ws + off;
        off += (bytes + 255) & ~(size_t)255;
        return p;
    };
    float* bufA   = (float*)alloc(N_NODES * 64 * sizeof(float));
    float* bufB   = (float*)alloc(N_NODES * 64 * sizeof(float));
    float* dinv   = (float*)alloc(N_NODES * sizeof(float));
    int*   cnt    = (int*)  alloc(N_NODES * sizeof(int));
    int*   rowp   = (int*)  alloc((N_NODES + 1) * sizeof(int));
    int*   cursor = (int*)  alloc(N_NODES * sizeof(int));
    int*   esrc   = (int*)  alloc(N_EDGES * sizeof(int));
    int*   gstart = (int*)  alloc((N_GRAPHS + 1) * sizeof(int));
    float* xgp    = (float*)alloc(N_GRAPHS * 64 * sizeof(float));
    float* xg     = (float*)alloc(N_GRAPHS * 64 * sizeof(float));
    (void)ws_size; (void)n_in; (void)in_sizes; (void)out_size;

    float* out_h = (float*)d_out;              // [256]
    float* out_m = (float*)d_out + 256;        // [100000*9]
    float* out_p = (float*)d_out + 256 + 900000; // [100000]

    const int TB = 256;
    dim3 blkN((N_NODES + TB - 1) / TB);
    dim3 blkE((N_EDGES + TB - 1) / TB);
    dim3 blkWave((N_NODES * 64 + TB - 1) / TB);  // one wave per node

    // CSR build
    k_zero_int<<<blkN, TB, 0, stream>>>(cnt, N_NODES);
    k_count<<<blkE, TB, 0, stream>>>(e_dst, cnt, N_EDGES);
    k_dinv<<<blkN, TB, 0, stream>>>(cnt, dinv, N_NODES);
    k_scan<<<1, 1024, 0, stream>>>(cnt, rowp, cursor, N_NODES);
    k_fill<<<blkE, TB, 0, stream>>>(e_src, e_dst, cursor, esrc, N_EDGES);

    // layer 1
    k_transform1<<<blkWave, TB, 0, stream>>>(x, W1, dinv, bufB);
    k_aggregate<1><<<blkWave, TB, 0, stream>>>(bufB, bufA, dinv, rowp, esrc, b1);
    // layer 2
    k_transform64<<<blkWave, TB, 0, stream>>>(bufA, W2, dinv, bufB);
    k_aggregate<1><<<blkWave, TB, 0, stream>>>(bufB, bufA, dinv, rowp, esrc, b2);
    // layer 3 (no relu)
    k_transform64<<<blkWave, TB, 0, stream>>>(bufA, W3, dinv, bufB);
    k_aggregate<0><<<blkWave, TB, 0, stream>>>(bufB, bufA, dinv, rowp, esrc, b3);

    // pooling + global head
    k_gstart<<<1, N_GRAPHS, 0, stream>>>(batch, gstart);
    k_pool<<<N_GRAPHS, TB, 0, stream>>>(bufA, gstart, xgp);
    k_xglobal<<<(N_GRAPHS * 64 + TB - 1) / TB, TB, 0, stream>>>(xgp, Wg, bg, xg);
    k_heuristic<<<1, N_GRAPHS, 0, stream>>>(xg, Wh1, bh1, Wh2, bh2, out_h);

    // node heads
    k_heads<<<blkWave, TB, 0, stream>>>(bufA, Wm1, bm1, Wm2, bm2,
                                        Wp1, bp1, Wp2, bp2, out_m, out_p);
}